// Round 3
// baseline (10893.130 us; speedup 1.0000x reference)
//
#include <hip/hip_runtime.h>
#include <cstdint>
#include <cstddef>

#define SEQ   512
#define BATCH 128
#define EMB   1024
#define HID   1024
#define VOCAB 50257
#define GATES 4096  // 4*HID

typedef _Float16 f16x8 __attribute__((ext_vector_type(8)));
typedef float    f32x4 __attribute__((ext_vector_type(4)));
typedef unsigned short u16;
typedef u16 u16x8 __attribute__((ext_vector_type(8)));  // 16-byte transfer unit

__device__ inline u16 f2h(float x) { union { _Float16 h; u16 u; } c; c.h = (_Float16)x; return c.u; }
__device__ inline float h2f(u16 u) { union { u16 u; _Float16 h; } c; c.u = u; return (float)c.h; }

__device__ inline void fence_rel_agent() { __builtin_amdgcn_fence(__ATOMIC_RELEASE, "agent"); }
__device__ inline void fence_acq_agent() { __builtin_amdgcn_fence(__ATOMIC_ACQUIRE, "agent"); }

// ---------------- prep kernels ----------------
__global__ void cast_f32_f16_kernel(const float* __restrict__ src, u16* __restrict__ dst, int n4) {
  int i = blockIdx.x * blockDim.x + threadIdx.x;
  int stride = gridDim.x * blockDim.x;
  for (; i < n4; i += stride) {
    float4 v = ((const float4*)src)[i];
    ushort4 o;
    o.x = f2h(v.x); o.y = f2h(v.y); o.z = f2h(v.z); o.w = f2h(v.w);
    ((ushort4*)dst)[i] = o;
  }
}

__global__ void init_kernel(const float* __restrict__ bih, const float* __restrict__ bhh,
                            float* __restrict__ bias, u16* __restrict__ h0, int* __restrict__ counter) {
  int i = blockIdx.x * blockDim.x + threadIdx.x;  // grid 128x256 = 32768
  if (i < GATES) bias[i] = bih[i] + bhh[i];
  ushort4 z; z.x = z.y = z.z = z.w = 0;
  ((ushort4*)h0)[i] = z;                          // 32768*4 = 131072 u16 = h slot 0
  if (i == 0) *counter = 0;
}

// ---------------- big GEMM: gates_x[t][n][b] = emb[X[t,b]] . W_ih[n] ----------------
// 128x128 tile, BK=32, fused embedding gather. Explicit VGPR->LDS staging (16B units).
// LDS layout per tile: [kq(4)][row(128)][8 f16] -> conflict-free b128 frag reads.
__global__ __launch_bounds__(256) void embed_gemm(
    const u16* __restrict__ embw, const u16* __restrict__ wih,
    const int* __restrict__ X, u16* __restrict__ gx, int t0)
{
  __shared__ u16 Als[4096];
  __shared__ u16 Bls[4096];
  const int tid = threadIdx.x;
  const int w = tid >> 6, lane = tid & 63;
  const int T = t0 + blockIdx.y;
  const int colbase = blockIdx.x << 7;
  const int wm = w & 1, wn = w >> 1;
  f32x4 acc[4][4] = {};
  const u16* afp = Als + (lane >> 4) * 1024 + (wm * 64 + (lane & 15)) * 8;
  const u16* bfp = Bls + (lane >> 4) * 1024 + (wn * 64 + (lane & 15)) * 8;

  // staging slots (16B each): idx = s*256+tid; bits: [9]=half(A/B), [8:7]=kq, [6:0]=row
  int skq[4], srow[4], shalf[4];
  size_t sg[4];
#pragma unroll
  for (int s = 0; s < 4; ++s) {
    const int idx = s * 256 + tid;
    shalf[s] = idx >> 9; skq[s] = (idx >> 7) & 3; srow[s] = idx & 127;
    if (shalf[s] == 0) sg[s] = (size_t)X[(size_t)T * BATCH + srow[s]] * EMB + skq[s] * 8;
    else               sg[s] = (size_t)(colbase + srow[s]) * EMB + skq[s] * 8;
  }

  for (int kit = 0; kit < 32; ++kit) {
    u16x8 v[4];
#pragma unroll
    for (int s = 0; s < 4; ++s)
      v[s] = *(const u16x8*)((shalf[s] ? wih : embw) + sg[s] + kit * 32);
#pragma unroll
    for (int s = 0; s < 4; ++s)
      *(u16x8*)((shalf[s] ? Bls : Als) + skq[s] * 1024 + srow[s] * 8) = v[s];
    __syncthreads();
    f16x8 af[4], bf[4];
#pragma unroll
    for (int mt = 0; mt < 4; ++mt) af[mt] = *(const f16x8*)(afp + mt * 128);
#pragma unroll
    for (int nt = 0; nt < 4; ++nt) bf[nt] = *(const f16x8*)(bfp + nt * 128);
#pragma unroll
    for (int mt = 0; mt < 4; ++mt)
#pragma unroll
      for (int nt = 0; nt < 4; ++nt)
        acc[mt][nt] = __builtin_amdgcn_mfma_f32_16x16x32_f16(af[mt], bf[nt], acc[mt][nt], 0, 0, 0);
    __syncthreads();
  }
  // store C as fp16, layout [t_local][n][b]; C/D map: col(n)=lane&15, row(b)=(lane>>4)*4+reg
  const size_t outbase = (size_t)blockIdx.y * ((size_t)GATES * BATCH);
#pragma unroll
  for (int mt = 0; mt < 4; ++mt) {
#pragma unroll
    for (int nt = 0; nt < 4; ++nt) {
      const int n = colbase + wn * 64 + nt * 16 + (lane & 15);
      const int b0 = wm * 64 + mt * 16 + ((lane >> 4) << 2);
      ushort4 o;
      o.x = f2h(acc[mt][nt][0]); o.y = f2h(acc[mt][nt][1]);
      o.z = f2h(acc[mt][nt][2]); o.w = f2h(acc[mt][nt][3]);
      *(ushort4*)(gx + outbase + (size_t)n * BATCH + b0) = o;
    }
  }
}

// ---------------- persistent LSTM recurrence ----------------
// G=128 WGs: blockIdx = (jw<<1)|bh. WG owns batch-half bh (64 rows), j-slice [jw*16,+16).
// W_hh slice (4 gates x 16 rows x 1024 k fp16 = 128KB) staged in LDS once per launch.
// h ring buffer slot layout: [jb=j>>3][b][j8] (u16); each 128B line written by ONE WG.
// Cross-XCD visibility: plain stores -> syncthreads (vmcnt drain) -> release fence
// (L2 writeback) -> atomic arrive -> spin -> acquire fence (L1/L2 inv) -> syncthreads.
__global__ __launch_bounds__(256) void lstm_kernel(
    const u16* __restrict__ whh, const float* __restrict__ bias,
    const u16* __restrict__ gx, u16* __restrict__ hring,
    float* __restrict__ cstate, float* __restrict__ hlast,
    int* __restrict__ counter, int t0, int t1)
{
  extern __shared__ u16 Wl[];  // 65536 u16: [g][ks][kq][i][8]
  const int tid = threadIdx.x;
  const int w = tid >> 6, lane = tid & 63;
  const int bh = blockIdx.x & 1;
  const int jw = blockIdx.x >> 1;
  const int G = gridDim.x;

  // stage W slice (16B units), global-coalesced: c bits = [g(2)][row i(4)][kc(7)]
  for (int c = tid; c < 8192; c += 256) {
    const int g = c >> 11, rem = c & 2047;
    const int i = rem >> 7, kc = rem & 127;
    const int ks = kc >> 2, kq = kc & 3;
    const size_t n = (size_t)g * HID + jw * 16 + i;
    u16x8 v = *(const u16x8*)(whh + n * HID + kc * 8);
    *(u16x8*)(Wl + (size_t)g * 16384 + ks * 512 + kq * 128 + i * 8) = v;
  }
  const int jloc = lane & 15;
  const int jglob = jw * 16 + jloc;
  const int bglob0 = bh * 64 + w * 16 + ((lane >> 4) << 2);
  const float bsI = bias[jglob], bsF = bias[HID + jglob];
  const float bsG = bias[2 * HID + jglob], bsO = bias[3 * HID + jglob];
  float cc[4];
  if (t0 == 0) { cc[0] = cc[1] = cc[2] = cc[3] = 0.f; }
  else {
#pragma unroll
    for (int p = 0; p < 4; ++p) cc[p] = cstate[(size_t)(bglob0 + p) * HID + jglob];
  }
  const int arow = bh * 64 + w * 16 + (lane & 15);
  const u16* abase = hring + (size_t)arow * 8 + (size_t)(lane >> 4) * 1024;
  const u16* wbase = Wl + (size_t)(lane >> 4) * 128 + jloc * 8;
  const int hw_idx0 = (jw * 2 + (jloc >> 3)) * 1024 + bglob0 * 8 + (jloc & 7);
  __syncthreads();

  for (int t = t0; t < t1; ++t) {
    const u16* ap = abase + (size_t)t * (BATCH * HID);
    const u16* gp = gx + (size_t)(t - t0) * ((size_t)GATES * BATCH);
    f32x4 a0 = {}, a1 = {}, a2 = {}, a3 = {};
#pragma unroll 8
    for (int ks = 0; ks < 32; ++ks) {
      f16x8 av = *(const f16x8*)(ap + ks * 4096);
      f16x8 w0 = *(const f16x8*)(wbase + ks * 512);
      f16x8 w1 = *(const f16x8*)(wbase + 16384 + ks * 512);
      f16x8 w2 = *(const f16x8*)(wbase + 32768 + ks * 512);
      f16x8 w3 = *(const f16x8*)(wbase + 49152 + ks * 512);
      a0 = __builtin_amdgcn_mfma_f32_16x16x32_f16(av, w0, a0, 0, 0, 0);
      a1 = __builtin_amdgcn_mfma_f32_16x16x32_f16(av, w1, a1, 0, 0, 0);
      a2 = __builtin_amdgcn_mfma_f32_16x16x32_f16(av, w2, a2, 0, 0, 0);
      a3 = __builtin_amdgcn_mfma_f32_16x16x32_f16(av, w3, a3, 0, 0, 0);
    }
    const ushort4 vI = *(const ushort4*)(gp + ((size_t)0 * HID + jglob) * BATCH + bglob0);
    const ushort4 vF = *(const ushort4*)(gp + ((size_t)1 * HID + jglob) * BATCH + bglob0);
    const ushort4 vG = *(const ushort4*)(gp + ((size_t)2 * HID + jglob) * BATCH + bglob0);
    const ushort4 vO = *(const ushort4*)(gp + ((size_t)3 * HID + jglob) * BATCH + bglob0);
    float xI[4] = { h2f(vI.x), h2f(vI.y), h2f(vI.z), h2f(vI.w) };
    float xF[4] = { h2f(vF.x), h2f(vF.y), h2f(vF.z), h2f(vF.w) };
    float xG[4] = { h2f(vG.x), h2f(vG.y), h2f(vG.z), h2f(vG.w) };
    float xO[4] = { h2f(vO.x), h2f(vO.y), h2f(vO.z), h2f(vO.w) };
    u16* hout = hring + (size_t)(t + 1) * (BATCH * HID);
#pragma unroll
    for (int p = 0; p < 4; ++p) {
      float gi = a0[p] + xI[p] + bsI;
      float gf = a1[p] + xF[p] + bsF;
      float gg = a2[p] + xG[p] + bsG;
      float go = a3[p] + xO[p] + bsO;
      float ii = 1.f / (1.f + __expf(-gi));
      float ff = 1.f / (1.f + __expf(-gf));
      float e2 = __expf(-2.f * fabsf(gg));
      float tg = copysignf((1.f - e2) / (1.f + e2), gg);
      float oo = 1.f / (1.f + __expf(-go));
      float cn = ff * cc[p] + ii * tg;
      cc[p] = cn;
      float e2c = __expf(-2.f * fabsf(cn));
      float tc = copysignf((1.f - e2c) / (1.f + e2c), cn);
      float hn = oo * tc;
      hout[hw_idx0 + p * 8] = f2h(hn);
      if (t + 1 == SEQ) hlast[(size_t)(bglob0 + p) * HID + jglob] = hn;
    }
    __syncthreads();  // drains each wave's vmcnt: all h stores at least in L2
    if (tid == 0) {
      fence_rel_agent();  // write back XCD L2 -> h visible at coherent point
      __hip_atomic_fetch_add(counter, 1, __ATOMIC_RELAXED, __HIP_MEMORY_SCOPE_AGENT);
      if (t + 1 < t1) {
        const int target = (t + 1) * G;
        while (__hip_atomic_load(counter, __ATOMIC_RELAXED, __HIP_MEMORY_SCOPE_AGENT) < target)
          __builtin_amdgcn_s_sleep(4);
        fence_acq_agent();  // invalidate L1 + XCD L2 -> no stale h lines
      }
    }
    __syncthreads();
  }
#pragma unroll
  for (int p = 0; p < 4; ++p) cstate[(size_t)(bglob0 + p) * HID + jglob] = cc[p];
}

// ---------------- log_softmax over BATCH axis ----------------
__global__ void logsoftmax_kernel(const float* __restrict__ hlast, float* __restrict__ out) {
  const int j = blockIdx.x * blockDim.x + threadIdx.x;
  if (j >= HID) return;
  float m = -1e30f;
  for (int b = 0; b < BATCH; ++b) m = fmaxf(m, hlast[(size_t)b * HID + j]);
  float s = 0.f;
  for (int b = 0; b < BATCH; ++b) s += expf(hlast[(size_t)b * HID + j] - m);
  const float lse = m + logf(s);
  for (int b = 0; b < BATCH; ++b) out[(size_t)b * HID + j] = hlast[(size_t)b * HID + j] - lse;
}

// ---------------- host ----------------
extern "C" void kernel_launch(void* const* d_in, const int* in_sizes, int n_in,
                              void* d_out, int out_size, void* d_ws, size_t ws_size,
                              hipStream_t stream) {
  const int*   X    = (const int*)d_in[0];
  const float* embd = (const float*)d_in[1];
  const float* wih  = (const float*)d_in[2];
  const float* whh  = (const float*)d_in[3];
  const float* bih  = (const float*)d_in[4];
  const float* bhh  = (const float*)d_in[5];
  float* out = (float*)d_out;

  char* p = (char*)d_ws;
  auto alloc = [&](size_t bytes) { char* r = p; p += (bytes + 255) & ~(size_t)255; return r; };
  u16*   embw    = (u16*)alloc((size_t)VOCAB * EMB * 2);
  u16*   wihh    = (u16*)alloc((size_t)GATES * EMB * 2);
  u16*   whhh    = (u16*)alloc((size_t)GATES * HID * 2);
  float* bias    = (float*)alloc((size_t)GATES * 4);
  u16*   hring   = (u16*)alloc((size_t)(SEQ + 1) * BATCH * HID * 2);
  float* hlast   = (float*)alloc((size_t)BATCH * HID * 4);
  float* cst     = (float*)alloc((size_t)BATCH * HID * 4);
  int*   counter = (int*)alloc(256);
  size_t used = (size_t)(p - (char*)d_ws);
  size_t avail = ws_size > used ? ws_size - used : 0;
  long long Tc = (long long)(avail / ((size_t)GATES * BATCH * 2));
  if (Tc > SEQ) Tc = SEQ;
  if (Tc < 1) return;  // insufficient workspace
  u16* gx = (u16*)alloc((size_t)Tc * GATES * BATCH * 2);

  hipFuncSetAttribute((const void*)lstm_kernel, hipFuncAttributeMaxDynamicSharedMemorySize, 131072);

  cast_f32_f16_kernel<<<2048, 256, 0, stream>>>(embd, embw, VOCAB * EMB / 4);
  cast_f32_f16_kernel<<<256, 256, 0, stream>>>(wih, wihh, GATES * EMB / 4);
  cast_f32_f16_kernel<<<256, 256, 0, stream>>>(whh, whhh, GATES * HID / 4);
  init_kernel<<<128, 256, 0, stream>>>(bih, bhh, bias, hring, counter);
  for (int t0 = 0; t0 < SEQ; t0 += (int)Tc) {
    const int t1 = (t0 + (int)Tc < SEQ) ? t0 + (int)Tc : SEQ;
    dim3 grid(32, t1 - t0);
    embed_gemm<<<grid, 256, 0, stream>>>(embw, wihh, X, gx, t0);
    lstm_kernel<<<128, 256, 131072, stream>>>(whhh, bias, gx, hring, cst, hlast, counter, t0, t1);
  }
  logsoftmax_kernel<<<4, 256, 0, stream>>>(hlast, out);
}

// Round 4
// 8732.858 us; speedup vs baseline: 1.2474x; 1.2474x over previous
//
#include <hip/hip_runtime.h>
#include <cstdint>
#include <cstddef>

#define SEQ   512
#define BATCH 128
#define EMB   1024
#define HID   1024
#define VOCAB 50257
#define GATES 4096  // 4*HID

typedef _Float16 f16x8 __attribute__((ext_vector_type(8)));
typedef float    f32x4 __attribute__((ext_vector_type(4)));
typedef unsigned short u16;
typedef u16 u16x8 __attribute__((ext_vector_type(8)));  // 16-byte transfer unit

__device__ inline u16 f2h(float x) { union { _Float16 h; u16 u; } c; c.h = (_Float16)x; return c.u; }
__device__ inline float h2f(u16 u) { union { u16 u; _Float16 h; } c; c.u = u; return (float)c.h; }

// ---------------- prep kernels ----------------
__global__ void cast_f32_f16_kernel(const float* __restrict__ src, u16* __restrict__ dst, int n4) {
  int i = blockIdx.x * blockDim.x + threadIdx.x;
  int stride = gridDim.x * blockDim.x;
  for (; i < n4; i += stride) {
    float4 v = ((const float4*)src)[i];
    ushort4 o;
    o.x = f2h(v.x); o.y = f2h(v.y); o.z = f2h(v.z); o.w = f2h(v.w);
    ((ushort4*)dst)[i] = o;
  }
}

__global__ void init_kernel(const float* __restrict__ bih, const float* __restrict__ bhh,
                            float* __restrict__ bias, u16* __restrict__ h0, int* __restrict__ counter) {
  int i = blockIdx.x * blockDim.x + threadIdx.x;  // grid 128x256 = 32768
  if (i < GATES) bias[i] = bih[i] + bhh[i];
  ushort4 z; z.x = z.y = z.z = z.w = 0;
  ((ushort4*)h0)[i] = z;                          // 32768*4 = 131072 u16 = h slot 0
  if (i == 0) *counter = 0;
}

// ---------------- big GEMM: gates_x[t][n][b] = emb[X[t,b]] . W_ih[n] ----------------
// 128x128 tile, BK=32, fused embedding gather. Explicit VGPR->LDS staging (16B units).
// LDS layout per tile: [kq(4)][row(128)][8 f16] -> conflict-free b128 frag reads.
__global__ __launch_bounds__(256) void embed_gemm(
    const u16* __restrict__ embw, const u16* __restrict__ wih,
    const int* __restrict__ X, u16* __restrict__ gx, int t0)
{
  __shared__ u16 Als[4096];
  __shared__ u16 Bls[4096];
  const int tid = threadIdx.x;
  const int w = tid >> 6, lane = tid & 63;
  const int T = t0 + blockIdx.y;
  const int colbase = blockIdx.x << 7;
  const int wm = w & 1, wn = w >> 1;
  f32x4 acc[4][4] = {};
  const u16* afp = Als + (lane >> 4) * 1024 + (wm * 64 + (lane & 15)) * 8;
  const u16* bfp = Bls + (lane >> 4) * 1024 + (wn * 64 + (lane & 15)) * 8;

  // staging slots (16B each): idx = s*256+tid; bits: [9]=half(A/B), [8:7]=kq, [6:0]=row
  int skq[4], srow[4], shalf[4];
  size_t sg[4];
#pragma unroll
  for (int s = 0; s < 4; ++s) {
    const int idx = s * 256 + tid;
    shalf[s] = idx >> 9; skq[s] = (idx >> 7) & 3; srow[s] = idx & 127;
    if (shalf[s] == 0) sg[s] = (size_t)X[(size_t)T * BATCH + srow[s]] * EMB + skq[s] * 8;
    else               sg[s] = (size_t)(colbase + srow[s]) * EMB + skq[s] * 8;
  }

  for (int kit = 0; kit < 32; ++kit) {
    u16x8 v[4];
#pragma unroll
    for (int s = 0; s < 4; ++s)
      v[s] = *(const u16x8*)((shalf[s] ? wih : embw) + sg[s] + kit * 32);
#pragma unroll
    for (int s = 0; s < 4; ++s)
      *(u16x8*)((shalf[s] ? Bls : Als) + skq[s] * 1024 + srow[s] * 8) = v[s];
    __syncthreads();
    f16x8 af[4], bf[4];
#pragma unroll
    for (int mt = 0; mt < 4; ++mt) af[mt] = *(const f16x8*)(afp + mt * 128);
#pragma unroll
    for (int nt = 0; nt < 4; ++nt) bf[nt] = *(const f16x8*)(bfp + nt * 128);
#pragma unroll
    for (int mt = 0; mt < 4; ++mt)
#pragma unroll
      for (int nt = 0; nt < 4; ++nt)
        acc[mt][nt] = __builtin_amdgcn_mfma_f32_16x16x32_f16(af[mt], bf[nt], acc[mt][nt], 0, 0, 0);
    __syncthreads();
  }
  // store C as fp16, layout [t_local][n][b]; C/D map: col(n)=lane&15, row(b)=(lane>>4)*4+reg
  const size_t outbase = (size_t)blockIdx.y * ((size_t)GATES * BATCH);
#pragma unroll
  for (int mt = 0; mt < 4; ++mt) {
#pragma unroll
    for (int nt = 0; nt < 4; ++nt) {
      const int n = colbase + wn * 64 + nt * 16 + (lane & 15);
      const int b0 = wm * 64 + mt * 16 + ((lane >> 4) << 2);
      ushort4 o;
      o.x = f2h(acc[mt][nt][0]); o.y = f2h(acc[mt][nt][1]);
      o.z = f2h(acc[mt][nt][2]); o.w = f2h(acc[mt][nt][3]);
      *(ushort4*)(gx + outbase + (size_t)n * BATCH + b0) = o;
    }
  }
}

// ---------------- persistent LSTM recurrence ----------------
// G=128 WGs: blockIdx = (jw<<1)|bh. WG owns batch-half bh (64 rows), j-slice [jw*16,+16).
// W_hh slice (4 gates x 16 rows x 1024 k fp16 = 128KB) staged in LDS once per launch.
// h ring buffer slot layout: [jb=j>>3][b][j8] (u16); each 128B line written by ONE WG.
// Cross-XCD h visibility WITHOUT cache-walk fences:
//   - h stores are relaxed agent-scope atomics (sc0 sc1 write-through to LLC)
//   - __syncthreads drains vmcnt -> stores complete before the arrive
//   - readers: every step reads VIRGIN ring addresses -> L1/L2 miss -> fresh LLC data
//     (same-XCD readers hit the written-through L2 line; also fresh)
__global__ __launch_bounds__(256) void lstm_kernel(
    const u16* __restrict__ whh, const float* __restrict__ bias,
    const u16* __restrict__ gx, u16* __restrict__ hring,
    float* __restrict__ cstate, float* __restrict__ hlast,
    int* __restrict__ counter, int t0, int t1)
{
  extern __shared__ u16 Wl[];  // 65536 u16: [g][ks][kq][i][8]
  const int tid = threadIdx.x;
  const int w = tid >> 6, lane = tid & 63;
  const int bh = blockIdx.x & 1;
  const int jw = blockIdx.x >> 1;
  const int G = gridDim.x;

  // stage W slice (16B units), global-coalesced: c bits = [g(2)][row i(4)][kc(7)]
  for (int c = tid; c < 8192; c += 256) {
    const int g = c >> 11, rem = c & 2047;
    const int i = rem >> 7, kc = rem & 127;
    const int ks = kc >> 2, kq = kc & 3;
    const size_t n = (size_t)g * HID + jw * 16 + i;
    u16x8 v = *(const u16x8*)(whh + n * HID + kc * 8);
    *(u16x8*)(Wl + (size_t)g * 16384 + ks * 512 + kq * 128 + i * 8) = v;
  }
  const int jloc = lane & 15;
  const int jglob = jw * 16 + jloc;
  const int bglob0 = bh * 64 + w * 16 + ((lane >> 4) << 2);
  const float bsI = bias[jglob], bsF = bias[HID + jglob];
  const float bsG = bias[2 * HID + jglob], bsO = bias[3 * HID + jglob];
  float cc[4];
  if (t0 == 0) { cc[0] = cc[1] = cc[2] = cc[3] = 0.f; }
  else {
#pragma unroll
    for (int p = 0; p < 4; ++p) cc[p] = cstate[(size_t)(bglob0 + p) * HID + jglob];
  }
  const int arow = bh * 64 + w * 16 + (lane & 15);
  const u16* abase = hring + (size_t)arow * 8 + (size_t)(lane >> 4) * 1024;
  const u16* wbase = Wl + (size_t)(lane >> 4) * 128 + jloc * 8;
  const int hw_idx0 = (jw * 2 + (jloc >> 3)) * 1024 + bglob0 * 8 + (jloc & 7);
  __syncthreads();

  for (int t = t0; t < t1; ++t) {
    const u16* ap = abase + (size_t)t * (BATCH * HID);
    const u16* gp = gx + (size_t)(t - t0) * ((size_t)GATES * BATCH);
    // gx loads are independent of the MFMA loop -> issue first, consume after
    const ushort4 vI = *(const ushort4*)(gp + ((size_t)0 * HID + jglob) * BATCH + bglob0);
    const ushort4 vF = *(const ushort4*)(gp + ((size_t)1 * HID + jglob) * BATCH + bglob0);
    const ushort4 vG = *(const ushort4*)(gp + ((size_t)2 * HID + jglob) * BATCH + bglob0);
    const ushort4 vO = *(const ushort4*)(gp + ((size_t)3 * HID + jglob) * BATCH + bglob0);
    f32x4 a0 = {}, a1 = {}, a2 = {}, a3 = {};
#pragma unroll 8
    for (int ks = 0; ks < 32; ++ks) {
      f16x8 av = *(const f16x8*)(ap + ks * 4096);
      f16x8 w0 = *(const f16x8*)(wbase + ks * 512);
      f16x8 w1 = *(const f16x8*)(wbase + 16384 + ks * 512);
      f16x8 w2 = *(const f16x8*)(wbase + 32768 + ks * 512);
      f16x8 w3 = *(const f16x8*)(wbase + 49152 + ks * 512);
      a0 = __builtin_amdgcn_mfma_f32_16x16x32_f16(av, w0, a0, 0, 0, 0);
      a1 = __builtin_amdgcn_mfma_f32_16x16x32_f16(av, w1, a1, 0, 0, 0);
      a2 = __builtin_amdgcn_mfma_f32_16x16x32_f16(av, w2, a2, 0, 0, 0);
      a3 = __builtin_amdgcn_mfma_f32_16x16x32_f16(av, w3, a3, 0, 0, 0);
    }
    float xI[4] = { h2f(vI.x), h2f(vI.y), h2f(vI.z), h2f(vI.w) };
    float xF[4] = { h2f(vF.x), h2f(vF.y), h2f(vF.z), h2f(vF.w) };
    float xG[4] = { h2f(vG.x), h2f(vG.y), h2f(vG.z), h2f(vG.w) };
    float xO[4] = { h2f(vO.x), h2f(vO.y), h2f(vO.z), h2f(vO.w) };
    u16* hout = hring + (size_t)(t + 1) * (BATCH * HID);
#pragma unroll
    for (int p = 0; p < 4; ++p) {
      float gi = a0[p] + xI[p] + bsI;
      float gf = a1[p] + xF[p] + bsF;
      float gg = a2[p] + xG[p] + bsG;
      float go = a3[p] + xO[p] + bsO;
      float ii = 1.f / (1.f + __expf(-gi));
      float ff = 1.f / (1.f + __expf(-gf));
      float e2 = __expf(-2.f * fabsf(gg));
      float tg = copysignf((1.f - e2) / (1.f + e2), gg);
      float oo = 1.f / (1.f + __expf(-go));
      float cn = ff * cc[p] + ii * tg;
      cc[p] = cn;
      float e2c = __expf(-2.f * fabsf(cn));
      float tc = copysignf((1.f - e2c) / (1.f + e2c), cn);
      float hn = oo * tc;
      // write-through to LLC (agent scope) so other XCDs' misses see fresh data
      __hip_atomic_store(hout + hw_idx0 + p * 8, f2h(hn),
                         __ATOMIC_RELAXED, __HIP_MEMORY_SCOPE_AGENT);
      if (t + 1 == SEQ) hlast[(size_t)(bglob0 + p) * HID + jglob] = hn;
    }
    __syncthreads();  // drains each wave's vmcnt: all h stores committed at LLC
    if (tid == 0) {
      __hip_atomic_fetch_add(counter, 1, __ATOMIC_RELAXED, __HIP_MEMORY_SCOPE_AGENT);
      if (t + 1 < t1) {
        const int target = (t + 1) * G;
        while (__hip_atomic_load(counter, __ATOMIC_RELAXED, __HIP_MEMORY_SCOPE_AGENT) < target)
          __builtin_amdgcn_s_sleep(2);
      }
    }
    __syncthreads();
  }
#pragma unroll
  for (int p = 0; p < 4; ++p) cstate[(size_t)(bglob0 + p) * HID + jglob] = cc[p];
}

// ---------------- log_softmax over BATCH axis ----------------
__global__ void logsoftmax_kernel(const float* __restrict__ hlast, float* __restrict__ out) {
  const int j = blockIdx.x * blockDim.x + threadIdx.x;
  if (j >= HID) return;
  float m = -1e30f;
  for (int b = 0; b < BATCH; ++b) m = fmaxf(m, hlast[(size_t)b * HID + j]);
  float s = 0.f;
  for (int b = 0; b < BATCH; ++b) s += expf(hlast[(size_t)b * HID + j] - m);
  const float lse = m + logf(s);
  for (int b = 0; b < BATCH; ++b) out[(size_t)b * HID + j] = hlast[(size_t)b * HID + j] - lse;
}

// ---------------- host ----------------
extern "C" void kernel_launch(void* const* d_in, const int* in_sizes, int n_in,
                              void* d_out, int out_size, void* d_ws, size_t ws_size,
                              hipStream_t stream) {
  const int*   X    = (const int*)d_in[0];
  const float* embd = (const float*)d_in[1];
  const float* wih  = (const float*)d_in[2];
  const float* whh  = (const float*)d_in[3];
  const float* bih  = (const float*)d_in[4];
  const float* bhh  = (const float*)d_in[5];
  float* out = (float*)d_out;

  char* p = (char*)d_ws;
  auto alloc = [&](size_t bytes) { char* r = p; p += (bytes + 255) & ~(size_t)255; return r; };
  u16*   embw    = (u16*)alloc((size_t)VOCAB * EMB * 2);
  u16*   wihh    = (u16*)alloc((size_t)GATES * EMB * 2);
  u16*   whhh    = (u16*)alloc((size_t)GATES * HID * 2);
  float* bias    = (float*)alloc((size_t)GATES * 4);
  u16*   hring   = (u16*)alloc((size_t)(SEQ + 1) * BATCH * HID * 2);
  float* hlast   = (float*)alloc((size_t)BATCH * HID * 4);
  float* cst     = (float*)alloc((size_t)BATCH * HID * 4);
  int*   counter = (int*)alloc(256);
  size_t used = (size_t)(p - (char*)d_ws);
  size_t avail = ws_size > used ? ws_size - used : 0;
  long long Tc = (long long)(avail / ((size_t)GATES * BATCH * 2));
  if (Tc > SEQ) Tc = SEQ;
  if (Tc < 1) return;  // insufficient workspace
  u16* gx = (u16*)alloc((size_t)Tc * GATES * BATCH * 2);

  hipFuncSetAttribute((const void*)lstm_kernel, hipFuncAttributeMaxDynamicSharedMemorySize, 131072);

  cast_f32_f16_kernel<<<2048, 256, 0, stream>>>(embd, embw, VOCAB * EMB / 4);
  cast_f32_f16_kernel<<<256, 256, 0, stream>>>(wih, wihh, GATES * EMB / 4);
  cast_f32_f16_kernel<<<256, 256, 0, stream>>>(whh, whhh, GATES * HID / 4);
  init_kernel<<<128, 256, 0, stream>>>(bih, bhh, bias, hring, counter);
  for (int t0 = 0; t0 < SEQ; t0 += (int)Tc) {
    const int t1 = (t0 + (int)Tc < SEQ) ? t0 + (int)Tc : SEQ;
    dim3 grid(32, t1 - t0);
    embed_gemm<<<grid, 256, 0, stream>>>(embw, wihh, X, gx, t0);
    lstm_kernel<<<128, 256, 131072, stream>>>(whhh, bias, gx, hring, cst, hlast, counter, t0, t1);
  }
  logsoftmax_kernel<<<4, 256, 0, stream>>>(hlast, out);
}

// Round 5
// 8258.279 us; speedup vs baseline: 1.3191x; 1.0575x over previous
//
#include <hip/hip_runtime.h>
#include <cstdint>
#include <cstddef>

#define SEQ   512
#define BATCH 128
#define EMB   1024
#define HID   1024
#define VOCAB 50257
#define GATES 4096  // 4*HID

typedef _Float16 f16x8 __attribute__((ext_vector_type(8)));
typedef float    f32x4 __attribute__((ext_vector_type(4)));
typedef unsigned short u16;
typedef u16 u16x8 __attribute__((ext_vector_type(8)));  // 16-byte transfer unit

__device__ inline u16 f2h(float x) { union { _Float16 h; u16 u; } c; c.h = (_Float16)x; return c.u; }
__device__ inline float h2f(u16 u) { union { u16 u; _Float16 h; } c; c.u = u; return (float)c.h; }

// ---------------- prep kernels ----------------
__global__ void cast_f32_f16_kernel(const float* __restrict__ src, u16* __restrict__ dst, int n4) {
  int i = blockIdx.x * blockDim.x + threadIdx.x;
  int stride = gridDim.x * blockDim.x;
  for (; i < n4; i += stride) {
    float4 v = ((const float4*)src)[i];
    ushort4 o;
    o.x = f2h(v.x); o.y = f2h(v.y); o.z = f2h(v.z); o.w = f2h(v.w);
    ((ushort4*)dst)[i] = o;
  }
}

__global__ void init_kernel(const float* __restrict__ bih, const float* __restrict__ bhh,
                            float* __restrict__ bias, u16* __restrict__ h0, int* __restrict__ sync) {
  int i = blockIdx.x * blockDim.x + threadIdx.x;  // grid 128x256 = 32768
  if (i < GATES) bias[i] = bih[i] + bhh[i];
  ushort4 z; z.x = z.y = z.z = z.w = 0;
  ((ushort4*)h0)[i] = z;                          // 32768*4 = 131072 u16 = h slot 0
  if (i < 8192) sync[i] = 0;                      // flags (128x32 ints) + release
}

// ---------------- big GEMM: gates_x[t][n][b] = emb[X[t,b]] . W_ih[n] ----------------
// 128x128 tile, BK=32, fused embedding gather. Explicit VGPR->LDS staging (16B units).
// LDS layout per tile: [kq(4)][row(128)][8 f16] -> conflict-free b128 frag reads.
__global__ __launch_bounds__(256) void embed_gemm(
    const u16* __restrict__ embw, const u16* __restrict__ wih,
    const int* __restrict__ X, u16* __restrict__ gx, int t0)
{
  __shared__ u16 Als[4096];
  __shared__ u16 Bls[4096];
  const int tid = threadIdx.x;
  const int w = tid >> 6, lane = tid & 63;
  const int T = t0 + blockIdx.y;
  const int colbase = blockIdx.x << 7;
  const int wm = w & 1, wn = w >> 1;
  f32x4 acc[4][4] = {};
  const u16* afp = Als + (lane >> 4) * 1024 + (wm * 64 + (lane & 15)) * 8;
  const u16* bfp = Bls + (lane >> 4) * 1024 + (wn * 64 + (lane & 15)) * 8;

  // staging slots (16B each): idx = s*256+tid; bits: [9]=half(A/B), [8:7]=kq, [6:0]=row
  int skq[4], srow[4], shalf[4];
  size_t sg[4];
#pragma unroll
  for (int s = 0; s < 4; ++s) {
    const int idx = s * 256 + tid;
    shalf[s] = idx >> 9; skq[s] = (idx >> 7) & 3; srow[s] = idx & 127;
    if (shalf[s] == 0) sg[s] = (size_t)X[(size_t)T * BATCH + srow[s]] * EMB + skq[s] * 8;
    else               sg[s] = (size_t)(colbase + srow[s]) * EMB + skq[s] * 8;
  }

  for (int kit = 0; kit < 32; ++kit) {
    u16x8 v[4];
#pragma unroll
    for (int s = 0; s < 4; ++s)
      v[s] = *(const u16x8*)((shalf[s] ? wih : embw) + sg[s] + kit * 32);
#pragma unroll
    for (int s = 0; s < 4; ++s)
      *(u16x8*)((shalf[s] ? Bls : Als) + skq[s] * 1024 + srow[s] * 8) = v[s];
    __syncthreads();
    f16x8 af[4], bf[4];
#pragma unroll
    for (int mt = 0; mt < 4; ++mt) af[mt] = *(const f16x8*)(afp + mt * 128);
#pragma unroll
    for (int nt = 0; nt < 4; ++nt) bf[nt] = *(const f16x8*)(bfp + nt * 128);
#pragma unroll
    for (int mt = 0; mt < 4; ++mt)
#pragma unroll
      for (int nt = 0; nt < 4; ++nt)
        acc[mt][nt] = __builtin_amdgcn_mfma_f32_16x16x32_f16(af[mt], bf[nt], acc[mt][nt], 0, 0, 0);
    __syncthreads();
  }
  // store C as fp16, layout [t_local][n][b]; C/D map: col(n)=lane&15, row(b)=(lane>>4)*4+reg
  const size_t outbase = (size_t)blockIdx.y * ((size_t)GATES * BATCH);
#pragma unroll
  for (int mt = 0; mt < 4; ++mt) {
#pragma unroll
    for (int nt = 0; nt < 4; ++nt) {
      const int n = colbase + wn * 64 + nt * 16 + (lane & 15);
      const int b0 = wm * 64 + mt * 16 + ((lane >> 4) << 2);
      ushort4 o;
      o.x = f2h(acc[mt][nt][0]); o.y = f2h(acc[mt][nt][1]);
      o.z = f2h(acc[mt][nt][2]); o.w = f2h(acc[mt][nt][3]);
      *(ushort4*)(gx + outbase + (size_t)n * BATCH + b0) = o;
    }
  }
}

// ---------------- persistent LSTM recurrence ----------------
// G=128 WGs: blockIdx = (jw<<1)|bh. WG owns batch-half bh (64 rows), j-slice [jw*16,+16).
// W_hh slice (4 gates x 16 rows x 1024 k fp16 = 128KB) staged in LDS once per launch.
// h ring buffer slot layout: [jb=j>>3][b][j8] (u16); each 128B line written by ONE WG.
// Cross-XCD h visibility WITHOUT cache-walk fences:
//   - h stores are relaxed agent-scope atomics (write-through to LLC)
//   - __syncthreads drains vmcnt -> stores complete before the flag arrive
//   - readers: every step reads VIRGIN ring addresses -> L1/L2 miss -> fresh LLC data
// Barrier: contention-free flat barrier. Each WG stores its OWN flag (128B-strided
// lines -> 128 parallel stores, no RMW serialization). WG0 wave0 gathers all 128
// flags (2 loads/lane + wave __all), then publishes a single release word that
// the other 127 WGs poll read-only.
__global__ __launch_bounds__(256) void lstm_kernel(
    const u16* __restrict__ whh, const float* __restrict__ bias,
    const u16* __restrict__ gx, u16* __restrict__ hring,
    float* __restrict__ cstate, float* __restrict__ hlast,
    int* __restrict__ flags, int* __restrict__ release, int t0, int t1)
{
  extern __shared__ u16 Wl[];  // 65536 u16: [g][ks][kq][i][8]
  const int tid = threadIdx.x;
  const int w = tid >> 6, lane = tid & 63;
  const int bh = blockIdx.x & 1;
  const int jw = blockIdx.x >> 1;

  // stage W slice (16B units), global-coalesced: c bits = [g(2)][row i(4)][kc(7)]
  for (int c = tid; c < 8192; c += 256) {
    const int g = c >> 11, rem = c & 2047;
    const int i = rem >> 7, kc = rem & 127;
    const int ks = kc >> 2, kq = kc & 3;
    const size_t n = (size_t)g * HID + jw * 16 + i;
    u16x8 v = *(const u16x8*)(whh + n * HID + kc * 8);
    *(u16x8*)(Wl + (size_t)g * 16384 + ks * 512 + kq * 128 + i * 8) = v;
  }
  const int jloc = lane & 15;
  const int jglob = jw * 16 + jloc;
  const int bglob0 = bh * 64 + w * 16 + ((lane >> 4) << 2);
  const float bsI = bias[jglob], bsF = bias[HID + jglob];
  const float bsG = bias[2 * HID + jglob], bsO = bias[3 * HID + jglob];
  float cc[4];
  if (t0 == 0) { cc[0] = cc[1] = cc[2] = cc[3] = 0.f; }
  else {
#pragma unroll
    for (int p = 0; p < 4; ++p) cc[p] = cstate[(size_t)(bglob0 + p) * HID + jglob];
  }
  const int arow = bh * 64 + w * 16 + (lane & 15);
  const u16* abase = hring + (size_t)arow * 8 + (size_t)(lane >> 4) * 1024;
  const u16* wbase = Wl + (size_t)(lane >> 4) * 128 + jloc * 8;
  const int hw_idx0 = (jw * 2 + (jloc >> 3)) * 1024 + bglob0 * 8 + (jloc & 7);
  __syncthreads();

  // gx fragment addresses (per lane), and prefetch for the first step
  const u16* gpI = gx + ((size_t)0 * HID + jglob) * BATCH + bglob0;
  const u16* gpF = gx + ((size_t)1 * HID + jglob) * BATCH + bglob0;
  const u16* gpG = gx + ((size_t)2 * HID + jglob) * BATCH + bglob0;
  const u16* gpO = gx + ((size_t)3 * HID + jglob) * BATCH + bglob0;
  ushort4 vI = *(const ushort4*)gpI;
  ushort4 vF = *(const ushort4*)gpF;
  ushort4 vG = *(const ushort4*)gpG;
  ushort4 vO = *(const ushort4*)gpO;

  for (int t = t0; t < t1; ++t) {
    const u16* ap = abase + (size_t)t * (BATCH * HID);
    f32x4 a0 = {}, a1 = {}, a2 = {}, a3 = {};
#pragma unroll 8
    for (int ks = 0; ks < 32; ++ks) {
      f16x8 av = *(const f16x8*)(ap + ks * 4096);
      f16x8 w0 = *(const f16x8*)(wbase + ks * 512);
      f16x8 w1 = *(const f16x8*)(wbase + 16384 + ks * 512);
      f16x8 w2 = *(const f16x8*)(wbase + 32768 + ks * 512);
      f16x8 w3 = *(const f16x8*)(wbase + 49152 + ks * 512);
      a0 = __builtin_amdgcn_mfma_f32_16x16x32_f16(av, w0, a0, 0, 0, 0);
      a1 = __builtin_amdgcn_mfma_f32_16x16x32_f16(av, w1, a1, 0, 0, 0);
      a2 = __builtin_amdgcn_mfma_f32_16x16x32_f16(av, w2, a2, 0, 0, 0);
      a3 = __builtin_amdgcn_mfma_f32_16x16x32_f16(av, w3, a3, 0, 0, 0);
    }
    float xI[4] = { h2f(vI.x), h2f(vI.y), h2f(vI.z), h2f(vI.w) };
    float xF[4] = { h2f(vF.x), h2f(vF.y), h2f(vF.z), h2f(vF.w) };
    float xG[4] = { h2f(vG.x), h2f(vG.y), h2f(vG.z), h2f(vG.w) };
    float xO[4] = { h2f(vO.x), h2f(vO.y), h2f(vO.z), h2f(vO.w) };
    u16* hout = hring + (size_t)(t + 1) * (BATCH * HID);
#pragma unroll
    for (int p = 0; p < 4; ++p) {
      float gi = a0[p] + xI[p] + bsI;
      float gf = a1[p] + xF[p] + bsF;
      float gg = a2[p] + xG[p] + bsG;
      float go = a3[p] + xO[p] + bsO;
      float ii = 1.f / (1.f + __expf(-gi));
      float ff = 1.f / (1.f + __expf(-gf));
      float e2 = __expf(-2.f * fabsf(gg));
      float tg = copysignf((1.f - e2) / (1.f + e2), gg);
      float oo = 1.f / (1.f + __expf(-go));
      float cn = ff * cc[p] + ii * tg;
      cc[p] = cn;
      float e2c = __expf(-2.f * fabsf(cn));
      float tc = copysignf((1.f - e2c) / (1.f + e2c), cn);
      float hn = oo * tc;
      // write-through to LLC (agent scope) so other XCDs' misses see fresh data
      __hip_atomic_store(hout + hw_idx0 + p * 8, f2h(hn),
                         __ATOMIC_RELAXED, __HIP_MEMORY_SCOPE_AGENT);
      if (t + 1 == SEQ) hlast[(size_t)(bglob0 + p) * HID + jglob] = hn;
    }
    // prefetch next step's gx fragment BEFORE the barrier (independent of h)
    if (t + 1 < t1) {
      const size_t off = (size_t)(t + 1 - t0) * ((size_t)GATES * BATCH);
      vI = *(const ushort4*)(gpI + off);
      vF = *(const ushort4*)(gpF + off);
      vG = *(const ushort4*)(gpG + off);
      vO = *(const ushort4*)(gpO + off);
    }
    __syncthreads();  // drains each wave's vmcnt: all h stores committed at LLC
    if (t + 1 < t1) {
      const int target = t + 1;
      if (tid == 0)
        __hip_atomic_store(flags + blockIdx.x * 32, target,
                           __ATOMIC_RELAXED, __HIP_MEMORY_SCOPE_AGENT);
      if (blockIdx.x == 0) {
        if (tid < 64) {
          const int* f0 = flags + tid * 32;
          const int* f1 = flags + (tid + 64) * 32;
          for (;;) {
            int a = __hip_atomic_load(f0, __ATOMIC_RELAXED, __HIP_MEMORY_SCOPE_AGENT);
            int b = __hip_atomic_load(f1, __ATOMIC_RELAXED, __HIP_MEMORY_SCOPE_AGENT);
            if (__all((a >= target) && (b >= target))) break;
            __builtin_amdgcn_s_sleep(1);
          }
          if (tid == 0)
            __hip_atomic_store(release, target, __ATOMIC_RELAXED, __HIP_MEMORY_SCOPE_AGENT);
        }
      } else if (tid == 0) {
        while (__hip_atomic_load(release, __ATOMIC_RELAXED, __HIP_MEMORY_SCOPE_AGENT) < target)
          __builtin_amdgcn_s_sleep(1);
      }
      __syncthreads();
    }
  }
#pragma unroll
  for (int p = 0; p < 4; ++p) cstate[(size_t)(bglob0 + p) * HID + jglob] = cc[p];
}

// ---------------- log_softmax over BATCH axis ----------------
__global__ void logsoftmax_kernel(const float* __restrict__ hlast, float* __restrict__ out) {
  const int j = blockIdx.x * blockDim.x + threadIdx.x;
  if (j >= HID) return;
  float m = -1e30f;
  for (int b = 0; b < BATCH; ++b) m = fmaxf(m, hlast[(size_t)b * HID + j]);
  float s = 0.f;
  for (int b = 0; b < BATCH; ++b) s += expf(hlast[(size_t)b * HID + j] - m);
  const float lse = m + logf(s);
  for (int b = 0; b < BATCH; ++b) out[(size_t)b * HID + j] = hlast[(size_t)b * HID + j] - lse;
}

// ---------------- host ----------------
extern "C" void kernel_launch(void* const* d_in, const int* in_sizes, int n_in,
                              void* d_out, int out_size, void* d_ws, size_t ws_size,
                              hipStream_t stream) {
  const int*   X    = (const int*)d_in[0];
  const float* embd = (const float*)d_in[1];
  const float* wih  = (const float*)d_in[2];
  const float* whh  = (const float*)d_in[3];
  const float* bih  = (const float*)d_in[4];
  const float* bhh  = (const float*)d_in[5];
  float* out = (float*)d_out;

  char* p = (char*)d_ws;
  auto alloc = [&](size_t bytes) { char* r = p; p += (bytes + 255) & ~(size_t)255; return r; };
  u16*   embw    = (u16*)alloc((size_t)VOCAB * EMB * 2);
  u16*   wihh    = (u16*)alloc((size_t)GATES * EMB * 2);
  u16*   whhh    = (u16*)alloc((size_t)GATES * HID * 2);
  float* bias    = (float*)alloc((size_t)GATES * 4);
  u16*   hring   = (u16*)alloc((size_t)(SEQ + 1) * BATCH * HID * 2);
  float* hlast   = (float*)alloc((size_t)BATCH * HID * 4);
  float* cst     = (float*)alloc((size_t)BATCH * HID * 4);
  int*   syncr   = (int*)alloc(32768);   // flags: 128x32 ints (128B stride); release at +4096
  int*   flags   = syncr;
  int*   release = syncr + 4096;
  size_t used = (size_t)(p - (char*)d_ws);
  size_t avail = ws_size > used ? ws_size - used : 0;
  long long Tc = (long long)(avail / ((size_t)GATES * BATCH * 2));
  if (Tc > SEQ) Tc = SEQ;
  if (Tc < 1) return;  // insufficient workspace
  u16* gx = (u16*)alloc((size_t)Tc * GATES * BATCH * 2);

  hipFuncSetAttribute((const void*)lstm_kernel, hipFuncAttributeMaxDynamicSharedMemorySize, 131072);

  cast_f32_f16_kernel<<<2048, 256, 0, stream>>>(embd, embw, VOCAB * EMB / 4);
  cast_f32_f16_kernel<<<256, 256, 0, stream>>>(wih, wihh, GATES * EMB / 4);
  cast_f32_f16_kernel<<<256, 256, 0, stream>>>(whh, whhh, GATES * HID / 4);
  init_kernel<<<128, 256, 0, stream>>>(bih, bhh, bias, hring, syncr);
  for (int t0 = 0; t0 < SEQ; t0 += (int)Tc) {
    const int t1 = (t0 + (int)Tc < SEQ) ? t0 + (int)Tc : SEQ;
    dim3 grid(32, t1 - t0);
    embed_gemm<<<grid, 256, 0, stream>>>(embw, wihh, X, gx, t0);
    lstm_kernel<<<128, 256, 131072, stream>>>(whhh, bias, gx, hring, cst, hlast, flags, release, t0, t1);
  }
  logsoftmax_kernel<<<4, 256, 0, stream>>>(hlast, out);
}

// Round 6
// 5769.768 us; speedup vs baseline: 1.8880x; 1.4313x over previous
//
#include <hip/hip_runtime.h>
#include <cstdint>
#include <cstddef>

#define SEQ   512
#define BATCH 128
#define EMB   1024
#define HID   1024
#define VOCAB 50257
#define GATES 4096  // 4*HID

typedef _Float16 f16x8 __attribute__((ext_vector_type(8)));
typedef float    f32x4 __attribute__((ext_vector_type(4)));
typedef unsigned short u16;
typedef u16 u16x8 __attribute__((ext_vector_type(8)));  // 16-byte transfer unit

__device__ inline u16 f2h(float x) { union { _Float16 h; u16 u; } c; c.h = (_Float16)x; return c.u; }
__device__ inline float h2f(u16 u) { union { u16 u; _Float16 h; } c; c.u = u; return (float)c.h; }

// ---------------- prep kernels ----------------
__global__ void cast_f32_f16_kernel(const float* __restrict__ src, u16* __restrict__ dst, int n4) {
  int i = blockIdx.x * blockDim.x + threadIdx.x;
  int stride = gridDim.x * blockDim.x;
  for (; i < n4; i += stride) {
    float4 v = ((const float4*)src)[i];
    ushort4 o;
    o.x = f2h(v.x); o.y = f2h(v.y); o.z = f2h(v.z); o.w = f2h(v.w);
    ((ushort4*)dst)[i] = o;
  }
}

__global__ void init_kernel(const float* __restrict__ bih, const float* __restrict__ bhh,
                            float* __restrict__ bias, u16* __restrict__ h0, int* __restrict__ sync) {
  int i = blockIdx.x * blockDim.x + threadIdx.x;  // grid 128x256 = 32768
  if (i < GATES) bias[i] = bih[i] + bhh[i];
  ushort4 z; z.x = z.y = z.z = z.w = 0;
  ((ushort4*)h0)[i] = z;                          // 32768*4 = 131072 u16 = h slot 0
  if (i < 8192) sync[i] = 0;                      // flags (128x32 ints) + release
}

// ---------------- big GEMM: gates_x[t][n][b] = emb[X[t,b]] . W_ih[n] ----------------
// 128x128 tile, BK=32, fused embedding gather. Explicit VGPR->LDS staging (16B units).
// LDS layout per tile: [kq(4)][row(128)][8 f16] -> conflict-free b128 frag reads.
__global__ __launch_bounds__(256) void embed_gemm(
    const u16* __restrict__ embw, const u16* __restrict__ wih,
    const int* __restrict__ X, u16* __restrict__ gx, int t0)
{
  __shared__ u16 Als[4096];
  __shared__ u16 Bls[4096];
  const int tid = threadIdx.x;
  const int w = tid >> 6, lane = tid & 63;
  const int T = t0 + blockIdx.y;
  const int colbase = blockIdx.x << 7;
  const int wm = w & 1, wn = w >> 1;
  f32x4 acc[4][4] = {};
  const u16* afp = Als + (lane >> 4) * 1024 + (wm * 64 + (lane & 15)) * 8;
  const u16* bfp = Bls + (lane >> 4) * 1024 + (wn * 64 + (lane & 15)) * 8;

  // staging slots (16B each): idx = s*256+tid; bits: [9]=half(A/B), [8:7]=kq, [6:0]=row
  int skq[4], srow[4], shalf[4];
  size_t sg[4];
#pragma unroll
  for (int s = 0; s < 4; ++s) {
    const int idx = s * 256 + tid;
    shalf[s] = idx >> 9; skq[s] = (idx >> 7) & 3; srow[s] = idx & 127;
    if (shalf[s] == 0) sg[s] = (size_t)X[(size_t)T * BATCH + srow[s]] * EMB + skq[s] * 8;
    else               sg[s] = (size_t)(colbase + srow[s]) * EMB + skq[s] * 8;
  }

  for (int kit = 0; kit < 32; ++kit) {
    u16x8 v[4];
#pragma unroll
    for (int s = 0; s < 4; ++s)
      v[s] = *(const u16x8*)((shalf[s] ? wih : embw) + sg[s] + kit * 32);
#pragma unroll
    for (int s = 0; s < 4; ++s)
      *(u16x8*)((shalf[s] ? Bls : Als) + skq[s] * 1024 + srow[s] * 8) = v[s];
    __syncthreads();
    f16x8 af[4], bf[4];
#pragma unroll
    for (int mt = 0; mt < 4; ++mt) af[mt] = *(const f16x8*)(afp + mt * 128);
#pragma unroll
    for (int nt = 0; nt < 4; ++nt) bf[nt] = *(const f16x8*)(bfp + nt * 128);
#pragma unroll
    for (int mt = 0; mt < 4; ++mt)
#pragma unroll
      for (int nt = 0; nt < 4; ++nt)
        acc[mt][nt] = __builtin_amdgcn_mfma_f32_16x16x32_f16(af[mt], bf[nt], acc[mt][nt], 0, 0, 0);
    __syncthreads();
  }
  // store C as fp16, layout [t_local][n][b]; C/D map: col(n)=lane&15, row(b)=(lane>>4)*4+reg
  const size_t outbase = (size_t)blockIdx.y * ((size_t)GATES * BATCH);
#pragma unroll
  for (int mt = 0; mt < 4; ++mt) {
#pragma unroll
    for (int nt = 0; nt < 4; ++nt) {
      const int n = colbase + wn * 64 + nt * 16 + (lane & 15);
      const int b0 = wm * 64 + mt * 16 + ((lane >> 4) << 2);
      ushort4 o;
      o.x = f2h(acc[mt][nt][0]); o.y = f2h(acc[mt][nt][1]);
      o.z = f2h(acc[mt][nt][2]); o.w = f2h(acc[mt][nt][3]);
      *(ushort4*)(gx + outbase + (size_t)n * BATCH + b0) = o;
    }
  }
}

// ---------------- persistent LSTM recurrence ----------------
// G=128 WGs: blockIdx = (jw<<1)|bh. WG owns batch-half bh (64 rows), j-slice [jw*16,+16).
// W_hh slice (4 gates x 16 rows x 1024 k fp16 = 128KB) staged in LDS once per launch.
// h ring buffer slot layout: [jb=j>>3][b][j8] (u16); each 128B line written by ONE WG.
// Cross-XCD h visibility WITHOUT cache-walk fences:
//   - h stores are relaxed agent-scope atomics (write-through to LLC)
//   - __syncthreads drains vmcnt -> stores complete before the flag arrive
//   - readers: every step reads VIRGIN ring addresses -> L1/L2 miss -> fresh LLC data
// Barrier: contention-free flat barrier (own-flag stores + WG0 gather + release).
// __launch_bounds__(256,1): allow ~512 VGPRs/wave so all 32 h-fragment loads can
// be preloaded and in flight simultaneously (we run 1 WG/CU by design anyway).
__global__ __launch_bounds__(256, 1) void lstm_kernel(
    const u16* __restrict__ whh, const float* __restrict__ bias,
    const u16* __restrict__ gx, u16* __restrict__ hring,
    float* __restrict__ cstate, float* __restrict__ hlast,
    int* __restrict__ flags, int* __restrict__ release, int t0, int t1)
{
  extern __shared__ u16 Wl[];  // 65536 u16: [g][ks][kq][i][8]
  const int tid = threadIdx.x;
  const int w = tid >> 6, lane = tid & 63;
  const int bh = blockIdx.x & 1;
  const int jw = blockIdx.x >> 1;

  // stage W slice (16B units), global-coalesced: c bits = [g(2)][row i(4)][kc(7)]
  for (int c = tid; c < 8192; c += 256) {
    const int g = c >> 11, rem = c & 2047;
    const int i = rem >> 7, kc = rem & 127;
    const int ks = kc >> 2, kq = kc & 3;
    const size_t n = (size_t)g * HID + jw * 16 + i;
    u16x8 v = *(const u16x8*)(whh + n * HID + kc * 8);
    *(u16x8*)(Wl + (size_t)g * 16384 + ks * 512 + kq * 128 + i * 8) = v;
  }
  const int jloc = lane & 15;
  const int jglob = jw * 16 + jloc;
  const int bglob0 = bh * 64 + w * 16 + ((lane >> 4) << 2);
  const float bsI = bias[jglob], bsF = bias[HID + jglob];
  const float bsG = bias[2 * HID + jglob], bsO = bias[3 * HID + jglob];
  float cc[4];
  if (t0 == 0) { cc[0] = cc[1] = cc[2] = cc[3] = 0.f; }
  else {
#pragma unroll
    for (int p = 0; p < 4; ++p) cc[p] = cstate[(size_t)(bglob0 + p) * HID + jglob];
  }
  const int arow = bh * 64 + w * 16 + (lane & 15);
  const u16* abase = hring + (size_t)arow * 8 + (size_t)(lane >> 4) * 1024;
  const u16* wbase = Wl + (size_t)(lane >> 4) * 128 + jloc * 8;
  const int hw_idx0 = (jw * 2 + (jloc >> 3)) * 1024 + bglob0 * 8 + (jloc & 7);
  __syncthreads();

  // gx fragment addresses (per lane), and prefetch for the first step
  const u16* gpI = gx + ((size_t)0 * HID + jglob) * BATCH + bglob0;
  const u16* gpF = gx + ((size_t)1 * HID + jglob) * BATCH + bglob0;
  const u16* gpG = gx + ((size_t)2 * HID + jglob) * BATCH + bglob0;
  const u16* gpO = gx + ((size_t)3 * HID + jglob) * BATCH + bglob0;
  ushort4 vI = *(const ushort4*)gpI;
  ushort4 vF = *(const ushort4*)gpF;
  ushort4 vG = *(const ushort4*)gpG;
  ushort4 vO = *(const ushort4*)gpO;

  for (int t = t0; t < t1; ++t) {
    const u16* ap = abase + (size_t)t * (BATCH * HID);
    // preload ALL 32 h fragments (128 VGPRs) -> loads pipeline instead of
    // serializing one L2-miss per MFMA iteration
    f16x8 av[32];
#pragma unroll
    for (int ks = 0; ks < 32; ++ks) av[ks] = *(const f16x8*)(ap + ks * 4096);
    f32x4 a0 = {}, a1 = {}, a2 = {}, a3 = {};
#pragma unroll
    for (int ks = 0; ks < 32; ++ks) {
      f16x8 w0 = *(const f16x8*)(wbase + ks * 512);
      f16x8 w1 = *(const f16x8*)(wbase + 16384 + ks * 512);
      f16x8 w2 = *(const f16x8*)(wbase + 32768 + ks * 512);
      f16x8 w3 = *(const f16x8*)(wbase + 49152 + ks * 512);
      a0 = __builtin_amdgcn_mfma_f32_16x16x32_f16(av[ks], w0, a0, 0, 0, 0);
      a1 = __builtin_amdgcn_mfma_f32_16x16x32_f16(av[ks], w1, a1, 0, 0, 0);
      a2 = __builtin_amdgcn_mfma_f32_16x16x32_f16(av[ks], w2, a2, 0, 0, 0);
      a3 = __builtin_amdgcn_mfma_f32_16x16x32_f16(av[ks], w3, a3, 0, 0, 0);
    }
    float xI[4] = { h2f(vI.x), h2f(vI.y), h2f(vI.z), h2f(vI.w) };
    float xF[4] = { h2f(vF.x), h2f(vF.y), h2f(vF.z), h2f(vF.w) };
    float xG[4] = { h2f(vG.x), h2f(vG.y), h2f(vG.z), h2f(vG.w) };
    float xO[4] = { h2f(vO.x), h2f(vO.y), h2f(vO.z), h2f(vO.w) };
    u16* hout = hring + (size_t)(t + 1) * (BATCH * HID);
#pragma unroll
    for (int p = 0; p < 4; ++p) {
      float gi = a0[p] + xI[p] + bsI;
      float gf = a1[p] + xF[p] + bsF;
      float gg = a2[p] + xG[p] + bsG;
      float go = a3[p] + xO[p] + bsO;
      float ii = 1.f / (1.f + __expf(-gi));
      float ff = 1.f / (1.f + __expf(-gf));
      float e2 = __expf(-2.f * fabsf(gg));
      float tg = copysignf((1.f - e2) / (1.f + e2), gg);
      float oo = 1.f / (1.f + __expf(-go));
      float cn = ff * cc[p] + ii * tg;
      cc[p] = cn;
      float e2c = __expf(-2.f * fabsf(cn));
      float tc = copysignf((1.f - e2c) / (1.f + e2c), cn);
      float hn = oo * tc;
      // write-through to LLC (agent scope) so other XCDs' misses see fresh data
      __hip_atomic_store(hout + hw_idx0 + p * 8, f2h(hn),
                         __ATOMIC_RELAXED, __HIP_MEMORY_SCOPE_AGENT);
      if (t + 1 == SEQ) hlast[(size_t)(bglob0 + p) * HID + jglob] = hn;
    }
    // prefetch next step's gx fragment BEFORE the barrier (independent of h)
    if (t + 1 < t1) {
      const size_t off = (size_t)(t + 1 - t0) * ((size_t)GATES * BATCH);
      vI = *(const ushort4*)(gpI + off);
      vF = *(const ushort4*)(gpF + off);
      vG = *(const ushort4*)(gpG + off);
      vO = *(const ushort4*)(gpO + off);
    }
    __syncthreads();  // drains each wave's vmcnt: all h stores committed at LLC
    if (t + 1 < t1) {
      const int target = t + 1;
      if (tid == 0)
        __hip_atomic_store(flags + blockIdx.x * 32, target,
                           __ATOMIC_RELAXED, __HIP_MEMORY_SCOPE_AGENT);
      if (blockIdx.x == 0) {
        if (tid < 64) {
          const int* f0 = flags + tid * 32;
          const int* f1 = flags + (tid + 64) * 32;
          for (;;) {
            int a = __hip_atomic_load(f0, __ATOMIC_RELAXED, __HIP_MEMORY_SCOPE_AGENT);
            int b = __hip_atomic_load(f1, __ATOMIC_RELAXED, __HIP_MEMORY_SCOPE_AGENT);
            if (__all((a >= target) && (b >= target))) break;
            __builtin_amdgcn_s_sleep(1);
          }
          if (tid == 0)
            __hip_atomic_store(release, target, __ATOMIC_RELAXED, __HIP_MEMORY_SCOPE_AGENT);
        }
      } else if (tid == 0) {
        while (__hip_atomic_load(release, __ATOMIC_RELAXED, __HIP_MEMORY_SCOPE_AGENT) < target)
          __builtin_amdgcn_s_sleep(1);
      }
      __syncthreads();
    }
  }
#pragma unroll
  for (int p = 0; p < 4; ++p) cstate[(size_t)(bglob0 + p) * HID + jglob] = cc[p];
}

// ---------------- log_softmax over BATCH axis ----------------
__global__ void logsoftmax_kernel(const float* __restrict__ hlast, float* __restrict__ out) {
  const int j = blockIdx.x * blockDim.x + threadIdx.x;
  if (j >= HID) return;
  float m = -1e30f;
  for (int b = 0; b < BATCH; ++b) m = fmaxf(m, hlast[(size_t)b * HID + j]);
  float s = 0.f;
  for (int b = 0; b < BATCH; ++b) s += expf(hlast[(size_t)b * HID + j] - m);
  const float lse = m + logf(s);
  for (int b = 0; b < BATCH; ++b) out[(size_t)b * HID + j] = hlast[(size_t)b * HID + j] - lse;
}

// ---------------- host ----------------
extern "C" void kernel_launch(void* const* d_in, const int* in_sizes, int n_in,
                              void* d_out, int out_size, void* d_ws, size_t ws_size,
                              hipStream_t stream) {
  const int*   X    = (const int*)d_in[0];
  const float* embd = (const float*)d_in[1];
  const float* wih  = (const float*)d_in[2];
  const float* whh  = (const float*)d_in[3];
  const float* bih  = (const float*)d_in[4];
  const float* bhh  = (const float*)d_in[5];
  float* out = (float*)d_out;

  char* p = (char*)d_ws;
  auto alloc = [&](size_t bytes) { char* r = p; p += (bytes + 255) & ~(size_t)255; return r; };
  u16*   embw    = (u16*)alloc((size_t)VOCAB * EMB * 2);
  u16*   wihh    = (u16*)alloc((size_t)GATES * EMB * 2);
  u16*   whhh    = (u16*)alloc((size_t)GATES * HID * 2);
  float* bias    = (float*)alloc((size_t)GATES * 4);
  u16*   hring   = (u16*)alloc((size_t)(SEQ + 1) * BATCH * HID * 2);
  float* hlast   = (float*)alloc((size_t)BATCH * HID * 4);
  float* cst     = (float*)alloc((size_t)BATCH * HID * 4);
  int*   syncr   = (int*)alloc(32768);   // flags: 128x32 ints (128B stride); release at +4096
  int*   flags   = syncr;
  int*   release = syncr + 4096;
  size_t used = (size_t)(p - (char*)d_ws);
  size_t avail = ws_size > used ? ws_size - used : 0;
  long long Tc = (long long)(avail / ((size_t)GATES * BATCH * 2));
  if (Tc > SEQ) Tc = SEQ;
  if (Tc < 1) return;  // insufficient workspace
  u16* gx = (u16*)alloc((size_t)Tc * GATES * BATCH * 2);

  hipFuncSetAttribute((const void*)lstm_kernel, hipFuncAttributeMaxDynamicSharedMemorySize, 131072);

  cast_f32_f16_kernel<<<2048, 256, 0, stream>>>(embd, embw, VOCAB * EMB / 4);
  cast_f32_f16_kernel<<<256, 256, 0, stream>>>(wih, wihh, GATES * EMB / 4);
  cast_f32_f16_kernel<<<256, 256, 0, stream>>>(whh, whhh, GATES * HID / 4);
  init_kernel<<<128, 256, 0, stream>>>(bih, bhh, bias, hring, syncr);
  for (int t0 = 0; t0 < SEQ; t0 += (int)Tc) {
    const int t1 = (t0 + (int)Tc < SEQ) ? t0 + (int)Tc : SEQ;
    dim3 grid(32, t1 - t0);
    embed_gemm<<<grid, 256, 0, stream>>>(embw, wihh, X, gx, t0);
    lstm_kernel<<<128, 256, 131072, stream>>>(whhh, bias, gx, hring, cst, hlast, flags, release, t0, t1);
  }
  logsoftmax_kernel<<<4, 256, 0, stream>>>(hlast, out);
}

// Round 7
// 5155.982 us; speedup vs baseline: 2.1127x; 1.1190x over previous
//
#include <hip/hip_runtime.h>
#include <cstdint>
#include <cstddef>

#define SEQ   512
#define BATCH 128
#define EMB   1024
#define HID   1024
#define VOCAB 50257
#define GATES 4096  // 4*HID

typedef _Float16 f16x8 __attribute__((ext_vector_type(8)));
typedef float    f32x4 __attribute__((ext_vector_type(4)));
typedef unsigned short u16;
typedef u16 u16x8 __attribute__((ext_vector_type(8)));  // 16-byte transfer unit

__device__ inline u16 f2h(float x) { union { _Float16 h; u16 u; } c; c.h = (_Float16)x; return c.u; }
__device__ inline float h2f(u16 u) { union { u16 u; _Float16 h; } c; c.u = u; return (float)c.h; }

// ---------------- prep kernels ----------------
__global__ void cast_f32_f16_kernel(const float* __restrict__ src, u16* __restrict__ dst, int n4) {
  int i = blockIdx.x * blockDim.x + threadIdx.x;
  int stride = gridDim.x * blockDim.x;
  for (; i < n4; i += stride) {
    float4 v = ((const float4*)src)[i];
    ushort4 o;
    o.x = f2h(v.x); o.y = f2h(v.y); o.z = f2h(v.z); o.w = f2h(v.w);
    ((ushort4*)dst)[i] = o;
  }
}

__global__ void init_kernel(const float* __restrict__ bih, const float* __restrict__ bhh,
                            float* __restrict__ bias, u16* __restrict__ h0, int* __restrict__ sync) {
  int i = blockIdx.x * blockDim.x + threadIdx.x;  // grid 128x256 = 32768
  if (i < GATES) bias[i] = bih[i] + bhh[i];
  ushort4 z; z.x = z.y = z.z = z.w = 0;
  ((ushort4*)h0)[i] = z;                          // 32768*4 = 131072 u16 = h slot 0
  if (i < 8192) sync[i] = 0;                      // flags (128x32 ints)
}

// ---------------- big GEMM: gates_x[t][b][n] = emb[X[t,b]] . W_ih[n] ----------------
// 128x128 tile, BK=32, fused embedding gather. Explicit VGPR->LDS staging (16B units).
// Output layout now [t][b][n] (b-major) so the LSTM epilogue lane (1 b x 4 j) reads ushort4.
__global__ __launch_bounds__(256) void embed_gemm(
    const u16* __restrict__ embw, const u16* __restrict__ wih,
    const int* __restrict__ X, u16* __restrict__ gx, int t0)
{
  __shared__ u16 Als[4096];
  __shared__ u16 Bls[4096];
  const int tid = threadIdx.x;
  const int w = tid >> 6, lane = tid & 63;
  const int T = t0 + blockIdx.y;
  const int colbase = blockIdx.x << 7;
  const int wm = w & 1, wn = w >> 1;
  f32x4 acc[4][4] = {};
  const u16* afp = Als + (lane >> 4) * 1024 + (wm * 64 + (lane & 15)) * 8;
  const u16* bfp = Bls + (lane >> 4) * 1024 + (wn * 64 + (lane & 15)) * 8;

  // staging slots (16B each): idx = s*256+tid; bits: [9]=half(A/B), [8:7]=kq, [6:0]=row
  int skq[4], srow[4], shalf[4];
  size_t sg[4];
#pragma unroll
  for (int s = 0; s < 4; ++s) {
    const int idx = s * 256 + tid;
    shalf[s] = idx >> 9; skq[s] = (idx >> 7) & 3; srow[s] = idx & 127;
    if (shalf[s] == 0) sg[s] = (size_t)X[(size_t)T * BATCH + srow[s]] * EMB + skq[s] * 8;
    else               sg[s] = (size_t)(colbase + srow[s]) * EMB + skq[s] * 8;
  }

  for (int kit = 0; kit < 32; ++kit) {
    u16x8 v[4];
#pragma unroll
    for (int s = 0; s < 4; ++s)
      v[s] = *(const u16x8*)((shalf[s] ? wih : embw) + sg[s] + kit * 32);
#pragma unroll
    for (int s = 0; s < 4; ++s)
      *(u16x8*)((shalf[s] ? Bls : Als) + skq[s] * 1024 + srow[s] * 8) = v[s];
    __syncthreads();
    f16x8 af[4], bf[4];
#pragma unroll
    for (int mt = 0; mt < 4; ++mt) af[mt] = *(const f16x8*)(afp + mt * 128);
#pragma unroll
    for (int nt = 0; nt < 4; ++nt) bf[nt] = *(const f16x8*)(bfp + nt * 128);
#pragma unroll
    for (int mt = 0; mt < 4; ++mt)
#pragma unroll
      for (int nt = 0; nt < 4; ++nt)
        acc[mt][nt] = __builtin_amdgcn_mfma_f32_16x16x32_f16(af[mt], bf[nt], acc[mt][nt], 0, 0, 0);
    __syncthreads();
  }
  // store C as fp16, layout [t_local][b][n]; C/D map: col(n)=lane&15, row(b)=(lane>>4)*4+reg
  const size_t outbase = (size_t)blockIdx.y * ((size_t)GATES * BATCH);
#pragma unroll
  for (int mt = 0; mt < 4; ++mt) {
#pragma unroll
    for (int nt = 0; nt < 4; ++nt) {
      const int n  = colbase + wn * 64 + nt * 16 + (lane & 15);
      const int b0 = wm * 64 + mt * 16 + ((lane >> 4) << 2);
#pragma unroll
      for (int p = 0; p < 4; ++p)
        gx[outbase + (size_t)(b0 + p) * GATES + n] = f2h(acc[mt][nt][p]);
    }
  }
}

// ---------------- persistent LSTM recurrence (operand-swapped, K-split) ----------------
// 128 WGs: blockIdx = (jw<<1)|bh. WG owns batch-half bh (64 rows), j-slice [jw*16,+16).
// MFMA: A = W (M=16 j, REGISTER-RESIDENT: 4g x 8ks x 4 VGPR = 128 VGPRs/wave),
//       B = h (N=16 batch, read directly from the ring buffer), D[m=j][n=b].
// Wave w owns k-quarter [w*256, +256) -> per-step cross-wave K-reduction via LDS
// (12 b128 writes + 12 reads per wave, conflict-free).  No W LDS stream at all.
// h ring slot layout [jb=j>>3][b][j8]; stores are relaxed agent-scope (write-through
// to LLC); readers always touch VIRGIN ring lines -> L2 miss -> fresh LLC data.
// Barrier: own-flag store + EVERY WG's wave0 polls all 128 flags (no release hop).
__global__ __launch_bounds__(256, 1) void lstm_kernel(
    const u16* __restrict__ whh, const float* __restrict__ bias,
    const u16* __restrict__ gx, u16* __restrict__ hring,
    float* __restrict__ cstate, float* __restrict__ hlast,
    int* __restrict__ flags, int t0, int t1)
{
  extern __shared__ u16 LdsRaw[];
  f32x4* Red = (f32x4*)LdsRaw;   // [w(4)][g(4)][nt(4)][lane(64)] f32x4 = 64 KB
  const int tid = threadIdx.x;
  const int w = tid >> 6, lane = tid & 63;
  const int jloc = lane & 15, lq = lane >> 4;
  const int bh = blockIdx.x & 1;
  const int jw = blockIdx.x >> 1;

  // persistent A-operand: W slice in registers. A[m=jloc][k = w*256 + ks*32 + lq*8 +0..7]
  f16x8 wreg[4][8];
#pragma unroll
  for (int g = 0; g < 4; ++g)
#pragma unroll
    for (int ks = 0; ks < 8; ++ks)
      wreg[g][ks] = *(const f16x8*)(whh + ((size_t)g * HID + jw * 16 + jloc) * HID
                                          + w * 256 + ks * 32 + lq * 8);

  const int b  = bh * 64 + w * 16 + jloc;   // epilogue-owned batch row
  const int j0 = jw * 16 + lq * 4;          // epilogue-owned j base (4 consecutive j)
  f32x4 bs[4];
#pragma unroll
  for (int g = 0; g < 4; ++g) bs[g] = *(const f32x4*)(bias + g * HID + j0);

  f32x4 cc;
  if (t0 == 0) { cc[0] = cc[1] = cc[2] = cc[3] = 0.f; }
  else cc = *(const f32x4*)(cstate + (size_t)b * HID + j0);

  // B-load base: jb = w*32 + ks*4 + lq ; b' = bh*64 + nt*16 + jloc
  const u16* hb = hring + (size_t)(w * 32 + lq) * 1024 + (size_t)(bh * 64 + jloc) * 8;
  // h-store index: 4 consecutive j within one octet -> one 8B store
  const int hw_idx = (jw * 2 + (lq >> 1)) * 1024 + b * 8 + (lq & 1) * 4;
  // gx per-lane base (u16 idx): [t][b][g*1024 + j0]
  const u16* gbase = gx + (size_t)b * GATES + j0;

  ushort4 vX[4];
#pragma unroll
  for (int g = 0; g < 4; ++g) vX[g] = *(const ushort4*)(gbase + g * 1024);

  for (int t = t0; t < t1; ++t) {
    const u16* ap = hb + (size_t)t * (BATCH * HID);
    // issue ALL 32 h-fragment loads back-to-back (pipelined LLC misses)
    f16x8 av[8][4];
#pragma unroll
    for (int ks = 0; ks < 8; ++ks)
#pragma unroll
      for (int nt = 0; nt < 4; ++nt)
        av[ks][nt] = *(const f16x8*)(ap + ks * 4096 + nt * 128);
    __builtin_amdgcn_sched_barrier(0);
    f32x4 acc[4][4] = {};
#pragma unroll
    for (int ks = 0; ks < 8; ++ks)
#pragma unroll
      for (int g = 0; g < 4; ++g)
#pragma unroll
        for (int nt = 0; nt < 4; ++nt)
          acc[g][nt] = __builtin_amdgcn_mfma_f32_16x16x32_f16(wreg[g][ks], av[ks][nt], acc[g][nt], 0, 0, 0);
    // cross-wave K reduction: wave w consumes nt==w outputs
#pragma unroll
    for (int g = 0; g < 4; ++g)
#pragma unroll
      for (int nt = 0; nt < 4; ++nt)
        if (nt != w) Red[((w * 4 + g) * 4 + nt) * 64 + lane] = acc[g][nt];
    __syncthreads();
    f32x4 gate[4];
#pragma unroll
    for (int g = 0; g < 4; ++g) {
      gate[g] = acc[g][w];
#pragma unroll
      for (int wp = 0; wp < 4; ++wp)
        if (wp != w) gate[g] += Red[((wp * 4 + g) * 4 + w) * 64 + lane];
    }
    u16* hout = hring + (size_t)(t + 1) * (BATCH * HID);
    float hn4[4];
#pragma unroll
    for (int p = 0; p < 4; ++p) {
      float gi = gate[0][p] + h2f(((const u16*)&vX[0])[p]) + bs[0][p];
      float gf = gate[1][p] + h2f(((const u16*)&vX[1])[p]) + bs[1][p];
      float gg = gate[2][p] + h2f(((const u16*)&vX[2])[p]) + bs[2][p];
      float go = gate[3][p] + h2f(((const u16*)&vX[3])[p]) + bs[3][p];
      float ii = 1.f / (1.f + __expf(-gi));
      float ff = 1.f / (1.f + __expf(-gf));
      float e2 = __expf(-2.f * fabsf(gg));
      float tg = copysignf((1.f - e2) / (1.f + e2), gg);
      float oo = 1.f / (1.f + __expf(-go));
      float cn = ff * cc[p] + ii * tg;
      cc[p] = cn;
      float e2c = __expf(-2.f * fabsf(cn));
      float tc = copysignf((1.f - e2c) / (1.f + e2c), cn);
      hn4[p] = oo * tc;
    }
    unsigned long long hp = (unsigned long long)f2h(hn4[0])
                          | ((unsigned long long)f2h(hn4[1]) << 16)
                          | ((unsigned long long)f2h(hn4[2]) << 32)
                          | ((unsigned long long)f2h(hn4[3]) << 48);
    __hip_atomic_store((unsigned long long*)(hout + hw_idx), hp,
                       __ATOMIC_RELAXED, __HIP_MEMORY_SCOPE_AGENT);
    if (t + 1 == SEQ) {
      float4 hl; hl.x = hn4[0]; hl.y = hn4[1]; hl.z = hn4[2]; hl.w = hn4[3];
      *(float4*)(hlast + (size_t)b * HID + j0) = hl;
    }
    // prefetch next step's gx fragment BEFORE the barrier (independent of h)
    if (t + 1 < t1) {
      const size_t off = (size_t)(t + 1 - t0) * ((size_t)GATES * BATCH);
#pragma unroll
      for (int g = 0; g < 4; ++g) vX[g] = *(const ushort4*)(gbase + off + g * 1024);
    }
    __syncthreads();  // drains each wave's vmcnt: all h stores committed at LLC; Red reuse fence
    if (t + 1 < t1) {
      const int target = t + 1;
      if (tid == 0)
        __hip_atomic_store(flags + blockIdx.x * 32, target,
                           __ATOMIC_RELAXED, __HIP_MEMORY_SCOPE_AGENT);
      if (tid < 64) {  // every WG's wave0 polls all 128 flags directly
        const int* f0 = flags + tid * 32;
        const int* f1 = flags + (tid + 64) * 32;
        for (;;) {
          int a = __hip_atomic_load(f0, __ATOMIC_RELAXED, __HIP_MEMORY_SCOPE_AGENT);
          int c2 = __hip_atomic_load(f1, __ATOMIC_RELAXED, __HIP_MEMORY_SCOPE_AGENT);
          if (__all((a >= target) && (c2 >= target))) break;
          __builtin_amdgcn_s_sleep(1);
        }
      }
      __syncthreads();
    }
  }
  *(f32x4*)(cstate + (size_t)b * HID + j0) = cc;
}

// ---------------- log_softmax over BATCH axis ----------------
__global__ void logsoftmax_kernel(const float* __restrict__ hlast, float* __restrict__ out) {
  const int j = blockIdx.x * blockDim.x + threadIdx.x;
  if (j >= HID) return;
  float m = -1e30f;
  for (int b = 0; b < BATCH; ++b) m = fmaxf(m, hlast[(size_t)b * HID + j]);
  float s = 0.f;
  for (int b = 0; b < BATCH; ++b) s += expf(hlast[(size_t)b * HID + j] - m);
  const float lse = m + logf(s);
  for (int b = 0; b < BATCH; ++b) out[(size_t)b * HID + j] = hlast[(size_t)b * HID + j] - lse;
}

// ---------------- host ----------------
extern "C" void kernel_launch(void* const* d_in, const int* in_sizes, int n_in,
                              void* d_out, int out_size, void* d_ws, size_t ws_size,
                              hipStream_t stream) {
  const int*   X    = (const int*)d_in[0];
  const float* embd = (const float*)d_in[1];
  const float* wih  = (const float*)d_in[2];
  const float* whh  = (const float*)d_in[3];
  const float* bih  = (const float*)d_in[4];
  const float* bhh  = (const float*)d_in[5];
  float* out = (float*)d_out;

  char* p = (char*)d_ws;
  auto alloc = [&](size_t bytes) { char* r = p; p += (bytes + 255) & ~(size_t)255; return r; };
  u16*   embw    = (u16*)alloc((size_t)VOCAB * EMB * 2);
  u16*   wihh    = (u16*)alloc((size_t)GATES * EMB * 2);
  u16*   whhh    = (u16*)alloc((size_t)GATES * HID * 2);
  float* bias    = (float*)alloc((size_t)GATES * 4);
  u16*   hring   = (u16*)alloc((size_t)(SEQ + 1) * BATCH * HID * 2);
  float* hlast   = (float*)alloc((size_t)BATCH * HID * 4);
  float* cst     = (float*)alloc((size_t)BATCH * HID * 4);
  int*   flags   = (int*)alloc(32768);   // 128 flags at 128B stride
  size_t used = (size_t)(p - (char*)d_ws);
  size_t avail = ws_size > used ? ws_size - used : 0;
  long long Tc = (long long)(avail / ((size_t)GATES * BATCH * 2));
  if (Tc > SEQ) Tc = SEQ;
  if (Tc < 1) return;  // insufficient workspace
  u16* gx = (u16*)alloc((size_t)Tc * GATES * BATCH * 2);

  hipFuncSetAttribute((const void*)lstm_kernel, hipFuncAttributeMaxDynamicSharedMemorySize, 65536);

  cast_f32_f16_kernel<<<2048, 256, 0, stream>>>(embd, embw, VOCAB * EMB / 4);
  cast_f32_f16_kernel<<<256, 256, 0, stream>>>(wih, wihh, GATES * EMB / 4);
  cast_f32_f16_kernel<<<256, 256, 0, stream>>>(whh, whhh, GATES * HID / 4);
  init_kernel<<<128, 256, 0, stream>>>(bih, bhh, bias, hring, flags);
  for (int t0 = 0; t0 < SEQ; t0 += (int)Tc) {
    const int t1 = (t0 + (int)Tc < SEQ) ? t0 + (int)Tc : SEQ;
    dim3 grid(32, t1 - t0);
    embed_gemm<<<grid, 256, 0, stream>>>(embw, wihh, X, gx, t0);
    lstm_kernel<<<128, 256, 65536, stream>>>(whhh, bias, gx, hring, cst, hlast, flags, t0, t1);
  }
  logsoftmax_kernel<<<4, 256, 0, stream>>>(hlast, out);
}